// Round 2
// baseline (624.333 us; speedup 1.0000x reference)
//
#include <hip/hip_runtime.h>
#include <hip/hip_bf16.h>
#include <stdint.h>

// y[b,s,o] = sum_i x[b,s,i] * (w[o,i]*mask[o,i]) + bias[o]
// Inputs fp32 (x [4,2048,4096], w [4096,4096], bias [4096], mask [4096,4096]),
// output fp32 [8192,4096]. Compute in bf16 MFMA (tolerance is bf16-floor).
// M = 8192, N = 4096, K = 4096.
#define M_DIM 8192
#define N_DIM 4096
#define K_DIM 4096
#define BM 128
#define BN 128
#define BK 32

typedef __attribute__((ext_vector_type(8))) __bf16 bf16x8;
typedef __attribute__((ext_vector_type(4))) float floatx4;

// ---------- fp32 -> bf16 (RNE) packing helpers ----------
__device__ inline unsigned f2b(float f) {
    union { float f; unsigned u; } v; v.f = f;
    return (v.u + 0x7FFFu + ((v.u >> 16) & 1u)) >> 16;   // RNE; inputs finite
}
__device__ inline unsigned pk2(float lo, float hi) {
    return (f2b(lo) & 0xFFFFu) | (f2b(hi) << 16);
}

// Async global->LDS, 16B/lane. LDS flat aperture is 4GB-aligned, so the low
// 32 bits of the flat pointer ARE the LDS byte offset (CK uses same trick).
__device__ inline void async_load16(const void* g, void* l) {
    __builtin_amdgcn_global_load_lds(
        (const __attribute__((address_space(1))) unsigned int*)(unsigned long long)g,
        (__attribute__((address_space(3))) unsigned int*)(unsigned int)(unsigned long long)l,
        16, 0, 0);
}

// ---------- Pass 1a: x fp32 -> bf16 ----------
__global__ __launch_bounds__(256)
void cvt_x_kernel(const float4* __restrict__ in, uint4* __restrict__ out, int n8) {
    int i = blockIdx.x * blockDim.x + threadIdx.x;
    if (i >= n8) return;
    float4 a = in[2 * i], b = in[2 * i + 1];
    uint4 o;
    o.x = pk2(a.x, a.y); o.y = pk2(a.z, a.w);
    o.z = pk2(b.x, b.y); o.w = pk2(b.z, b.w);
    out[i] = o;
}

// ---------- Pass 1b: wb = bf16(w * mask) ----------
__global__ __launch_bounds__(256)
void cvt_w_kernel(const float4* __restrict__ w, const float4* __restrict__ m,
                  uint4* __restrict__ out, int n8) {
    int i = blockIdx.x * blockDim.x + threadIdx.x;
    if (i >= n8) return;
    float4 w0 = w[2 * i], w1 = w[2 * i + 1];
    float4 m0 = m[2 * i], m1 = m[2 * i + 1];
    uint4 o;
    o.x = pk2(w0.x * m0.x, w0.y * m0.y);
    o.y = pk2(w0.z * m0.z, w0.w * m0.w);
    o.z = pk2(w1.x * m1.x, w1.y * m1.y);
    o.w = pk2(w1.z * m1.z, w1.w * m1.w);
    out[i] = o;
}

// ---------- Pass 2: C = A @ B^T + bias. A,B bf16 (from ws), C fp32 ----------
// m97 structure: 128x128 tile, BK=32, 4 waves 2x2, 4x4 mfma_16x16x32_bf16.
__global__ __launch_bounds__(256)
void gemm_bt_bias(const __hip_bfloat16* __restrict__ A,
                  const __hip_bfloat16* __restrict__ B,
                  const float* __restrict__ bias,
                  float* __restrict__ C) {
    __shared__ __hip_bfloat16 As[BM * BK];   // 8 KB
    __shared__ __hip_bfloat16 Bs[BN * BK];   // 8 KB

    const int t    = threadIdx.x;
    const int lane = t & 63;
    const int wave = t >> 6;
    const int wm   = wave >> 1;
    const int wn   = wave & 1;
    const int m0   = blockIdx.y * BM;
    const int n0   = blockIdx.x * BN;

    const int lm = lane & 15;
    const int lk = (lane >> 4) << 3;

    floatx4 acc[4][4] = {};

    // Staging: 128x32 bf16 tile = 512 x 16B chunks; chunk c -> row c/4,
    // k-sub (c%4)*8, LDS offset c*16B (contiguous in lane order per wave).
    const int c0 = t, c1 = t + 256;
    const int ar0 = c0 >> 2, ak0 = (c0 & 3) << 3;
    const int ar1 = c1 >> 2, ak1 = (c1 & 3) << 3;

    const __hip_bfloat16* Ab = A + (size_t)m0 * K_DIM;
    const __hip_bfloat16* Bb = B + (size_t)n0 * K_DIM;

    for (int k0 = 0; k0 < K_DIM; k0 += BK) {
        async_load16(Ab + (size_t)ar0 * K_DIM + k0 + ak0, As + c0 * 8);
        async_load16(Ab + (size_t)ar1 * K_DIM + k0 + ak1, As + c1 * 8);
        async_load16(Bb + (size_t)ar0 * K_DIM + k0 + ak0, Bs + c0 * 8);
        async_load16(Bb + (size_t)ar1 * K_DIM + k0 + ak1, Bs + c1 * 8);
        __syncthreads();   // drains vmcnt -> staged tiles visible

        bf16x8 af[4], bfr[4];
#pragma unroll
        for (int i = 0; i < 4; i++)
            af[i] = *reinterpret_cast<const bf16x8*>(
                &As[(wm * 64 + i * 16 + lm) * BK + lk]);
#pragma unroll
        for (int j = 0; j < 4; j++)
            bfr[j] = *reinterpret_cast<const bf16x8*>(
                &Bs[(wn * 64 + j * 16 + lm) * BK + lk]);
#pragma unroll
        for (int i = 0; i < 4; i++)
#pragma unroll
            for (int j = 0; j < 4; j++)
                acc[i][j] = __builtin_amdgcn_mfma_f32_16x16x32_bf16(
                    af[i], bfr[j], acc[i][j], 0, 0, 0);
        __syncthreads();
    }

    // Epilogue. C/D layout: col = lane&15, row = (lane>>4)*4 + reg.
    float bv[4];
#pragma unroll
    for (int j = 0; j < 4; j++)
        bv[j] = bias[n0 + wn * 64 + j * 16 + lm];
    const int row_base = m0 + wm * 64 + (lane >> 4) * 4;
    const int col_base = n0 + wn * 64 + lm;
#pragma unroll
    for (int i = 0; i < 4; i++)
#pragma unroll
        for (int j = 0; j < 4; j++) {
            const int col = col_base + j * 16;
#pragma unroll
            for (int r = 0; r < 4; r++)
                C[(size_t)(row_base + i * 16 + r) * N_DIM + col] =
                    acc[i][j][r] + bv[j];
        }
}

// ---------- Fallback: fuse fp32->bf16 + mask into staging (no ws needed) ----
__global__ __launch_bounds__(256)
void gemm_fused_f32(const float* __restrict__ A, const float* __restrict__ W,
                    const float* __restrict__ Mk, const float* __restrict__ bias,
                    float* __restrict__ C) {
    __shared__ __hip_bfloat16 As[BM * BK];
    __shared__ __hip_bfloat16 Bs[BN * BK];

    const int t    = threadIdx.x;
    const int lane = t & 63;
    const int wave = t >> 6;
    const int wm   = wave >> 1;
    const int wn   = wave & 1;
    const int m0   = blockIdx.y * BM;
    const int n0   = blockIdx.x * BN;
    const int lm = lane & 15;
    const int lk = (lane >> 4) << 3;

    floatx4 acc[4][4] = {};

    // Each thread stages 16 contiguous elements of one row for A and for B.
    const int r  = t >> 1;            // 0..127
    const int cb = (t & 1) * 16;      // 0 or 16

    for (int k0 = 0; k0 < K_DIM; k0 += BK) {
        const float* ap = A + (size_t)(m0 + r) * K_DIM + k0 + cb;
        float4 f0 = ((const float4*)ap)[0], f1 = ((const float4*)ap)[1];
        float4 f2 = ((const float4*)ap)[2], f3 = ((const float4*)ap)[3];
        uint4 pa, pb;
        pa.x = pk2(f0.x, f0.y); pa.y = pk2(f0.z, f0.w);
        pa.z = pk2(f1.x, f1.y); pa.w = pk2(f1.z, f1.w);
        pb.x = pk2(f2.x, f2.y); pb.y = pk2(f2.z, f2.w);
        pb.z = pk2(f3.x, f3.y); pb.w = pk2(f3.z, f3.w);
        *(uint4*)&As[r * BK + cb] = pa;
        *(uint4*)&As[r * BK + cb + 8] = pb;

        const float* wp = W + (size_t)(n0 + r) * K_DIM + k0 + cb;
        const float* mp = Mk + (size_t)(n0 + r) * K_DIM + k0 + cb;
        float4 w0 = ((const float4*)wp)[0], w1 = ((const float4*)wp)[1];
        float4 w2 = ((const float4*)wp)[2], w3 = ((const float4*)wp)[3];
        float4 q0 = ((const float4*)mp)[0], q1 = ((const float4*)mp)[1];
        float4 q2 = ((const float4*)mp)[2], q3 = ((const float4*)mp)[3];
        pa.x = pk2(w0.x * q0.x, w0.y * q0.y); pa.y = pk2(w0.z * q0.z, w0.w * q0.w);
        pa.z = pk2(w1.x * q1.x, w1.y * q1.y); pa.w = pk2(w1.z * q1.z, w1.w * q1.w);
        pb.x = pk2(w2.x * q2.x, w2.y * q2.y); pb.y = pk2(w2.z * q2.z, w2.w * q2.w);
        pb.z = pk2(w3.x * q3.x, w3.y * q3.y); pb.w = pk2(w3.z * q3.z, w3.w * q3.w);
        *(uint4*)&Bs[r * BK + cb] = pa;
        *(uint4*)&Bs[r * BK + cb + 8] = pb;
        __syncthreads();

        bf16x8 af[4], bfr[4];
#pragma unroll
        for (int i = 0; i < 4; i++)
            af[i] = *reinterpret_cast<const bf16x8*>(
                &As[(wm * 64 + i * 16 + lm) * BK + lk]);
#pragma unroll
        for (int j = 0; j < 4; j++)
            bfr[j] = *reinterpret_cast<const bf16x8*>(
                &Bs[(wn * 64 + j * 16 + lm) * BK + lk]);
#pragma unroll
        for (int i = 0; i < 4; i++)
#pragma unroll
            for (int j = 0; j < 4; j++)
                acc[i][j] = __builtin_amdgcn_mfma_f32_16x16x32_bf16(
                    af[i], bfr[j], acc[i][j], 0, 0, 0);
        __syncthreads();
    }

    float bv[4];
#pragma unroll
    for (int j = 0; j < 4; j++)
        bv[j] = bias[n0 + wn * 64 + j * 16 + lm];
    const int row_base = m0 + wm * 64 + (lane >> 4) * 4;
    const int col_base = n0 + wn * 64 + lm;
#pragma unroll
    for (int i = 0; i < 4; i++)
#pragma unroll
        for (int j = 0; j < 4; j++) {
            const int col = col_base + j * 16;
#pragma unroll
            for (int r4 = 0; r4 < 4; r4++)
                C[(size_t)(row_base + i * 16 + r4) * N_DIM + col] =
                    acc[i][j][r4] + bv[j];
        }
}

extern "C" void kernel_launch(void* const* d_in, const int* in_sizes, int n_in,
                              void* d_out, int out_size, void* d_ws, size_t ws_size,
                              hipStream_t stream) {
    const float* x    = (const float*)d_in[0];   // [4,2048,4096] fp32
    const float* w    = (const float*)d_in[1];   // [4096,4096] fp32
    const float* bias = (const float*)d_in[2];   // [4096] fp32
    const float* mask = (const float*)d_in[3];   // [4096,4096] fp32
    float* out = (float*)d_out;                  // [8192,4096] fp32

    const size_t xb_bytes = (size_t)M_DIM * K_DIM * 2;   // 64 MiB bf16 x
    const size_t wb_bytes = (size_t)N_DIM * K_DIM * 2;   // 32 MiB bf16 w*mask
    dim3 grid(N_DIM / BN, M_DIM / BM);   // 32 x 64 = 2048 blocks
    dim3 block(256);

    if (ws_size >= xb_bytes + wb_bytes) {
        __hip_bfloat16* xb = (__hip_bfloat16*)d_ws;
        __hip_bfloat16* wb = (__hip_bfloat16*)((char*)d_ws + xb_bytes);

        const int nx8 = M_DIM * K_DIM / 8;   // 4,194,304
        cvt_x_kernel<<<dim3(nx8 / 256), block, 0, stream>>>(
            (const float4*)x, (uint4*)xb, nx8);
        const int nw8 = N_DIM * K_DIM / 8;   // 2,097,152
        cvt_w_kernel<<<dim3(nw8 / 256), block, 0, stream>>>(
            (const float4*)w, (const float4*)mask, (uint4*)wb, nw8);
        gemm_bt_bias<<<grid, block, 0, stream>>>(xb, wb, bias, out);
    } else {
        gemm_fused_f32<<<grid, block, 0, stream>>>(x, w, mask, bias, out);
    }
}